// Round 6
// baseline (1304.267 us; speedup 1.0000x reference)
//
#include <hip/hip_runtime.h>
#include <math.h>

#define N_TOK 16384
#define HDIM 2048
#define NE 64
#define TOPK 8
#define NB 4
#define SEQ 4096
#define TT 64        // tokens per block
#define HC 64        // H-chunk staged per iteration
#define LSTR 68      // LDS staging row stride (floats): 68%32=4 -> 2-way alias (free)
#define SSTR 65      // score tile row stride

// fp32 multiply whose result cannot be contracted into an FMA by the compiler
// (numpy SSE3-baseline npyv_muladd is mul+add with SEPARATE rounding).
__device__ __forceinline__ float mul_nf(float a, float b) {
    float p = a * b;
    asm("" : "+v"(p));
    return p;
}

__global__ __launch_bounds__(256) void moe_gate_main(
    const float* __restrict__ x, const float* __restrict__ w,
    float* __restrict__ out_idx, float* __restrict__ out_w,
    float* __restrict__ ws_ce, float* __restrict__ ws_ssum)
{
    __shared__ float xs[TT][LSTR];
    __shared__ float wl[NE][LSTR];
    __shared__ float sc[TT][SSTR];
    __shared__ unsigned ce_loc[NE];
    __shared__ float sred[4][NE];

    const int tid = threadIdx.x;
    const int blk = blockIdx.x;
    const int t0  = blk * TT;
    const int tx  = tid & 15;   // expert group: experts {tx, tx+16, tx+32, tx+48}
    const int ty  = tid >> 4;   // token group:  tokens  {ty, ty+16, ty+32, ty+48}

    if (tid < NE) ce_loc[tid] = 0u;

    // np.einsum fp32 emulation: 4 lane-partials per (token,expert).
    // lane l accumulates products at h ≡ l (mod 4).
    float4 acc[4][4];
    #pragma unroll
    for (int i = 0; i < 4; ++i)
        #pragma unroll
        for (int j = 0; j < 4; ++j) acc[i][j] = make_float4(0.f, 0.f, 0.f, 0.f);

    // register prefetch buffers (double-buffer the global->LDS staging)
    float4 xr[4], wr[4];
    #pragma unroll
    for (int r = 0; r < 4; ++r) {
        int f = tid + r * 256;              // flat float4 index in [0,1024)
        int row = f >> 4, h4 = f & 15;      // 16 float4 per 64-float row
        xr[r] = *(const float4*)&x[(long)(t0 + row) * HDIM + (h4 << 2)];
        wr[r] = *(const float4*)&w[(long)row * HDIM + (h4 << 2)];
    }

    // numpy einsum x4-unroll chain adds sub-vectors in order 3,2,1,0 within
    // each 16-float block; blocks ascend.  h4 visit order per 64-float chunk:
    const int qord[16] = {3,2,1,0, 7,6,5,4, 11,10,9,8, 15,14,13,12};

    for (int hc = 0; hc < HDIM; hc += HC) {
        #pragma unroll
        for (int r = 0; r < 4; ++r) {
            int f = tid + r * 256;
            int row = f >> 4, h4 = f & 15;
            *(float4*)&xs[row][h4 << 2] = xr[r];
            *(float4*)&wl[row][h4 << 2] = wr[r];
        }
        __syncthreads();
        if (hc + HC < HDIM) {
            #pragma unroll
            for (int r = 0; r < 4; ++r) {
                int f = tid + r * 256;
                int row = f >> 4, h4 = f & 15;
                xr[r] = *(const float4*)&x[(long)(t0 + row) * HDIM + hc + HC + (h4 << 2)];
                wr[r] = *(const float4*)&w[(long)row * HDIM + hc + HC + (h4 << 2)];
            }
        }
        #pragma unroll
        for (int qi = 0; qi < 16; ++qi) {
            const int h4 = qord[qi];
            float4 xv[4], wv[4];
            #pragma unroll
            for (int i = 0; i < 4; ++i) xv[i] = *(const float4*)&xs[ty + 16 * i][h4 << 2];
            #pragma unroll
            for (int j = 0; j < 4; ++j) wv[j] = *(const float4*)&wl[tx + 16 * j][h4 << 2];
            #pragma unroll
            for (int i = 0; i < 4; ++i)
                #pragma unroll
                for (int j = 0; j < 4; ++j) {
                    acc[i][j].x = acc[i][j].x + mul_nf(xv[i].x, wv[j].x);
                    acc[i][j].y = acc[i][j].y + mul_nf(xv[i].y, wv[j].y);
                    acc[i][j].z = acc[i][j].z + mul_nf(xv[i].z, wv[j].z);
                    acc[i][j].w = acc[i][j].w + mul_nf(xv[i].w, wv[j].w);
                }
        }
        __syncthreads();
    }

    // horizontal combine, numpy npyv_sum (SSE3 hadd): (s0+s1)+(s2+s3)
    #pragma unroll
    for (int i = 0; i < 4; ++i)
        #pragma unroll
        for (int j = 0; j < 4; ++j) {
            float4 a = acc[i][j];
            sc[ty + 16 * i][tx + 16 * j] = (a.x + a.y) + (a.z + a.w);
        }
    __syncthreads();

    // epilogue: per wave, lane = expert; 16 tokens per wave (numpy fp32 emulation)
    const int wid  = tid >> 6;
    const int lane = tid & 63;
    const int b    = blk >> 6;          // SEQ/TT = 64 blocks per batch
    float ssum = 0.f;

    for (int r = 0; r < 16; ++r) {
        const int tok = wid * 16 + r;
        const float v = sc[tok][lane];
        // max over 64 experts (exact, order-free)
        float m = v;
        #pragma unroll
        for (int off = 32; off; off >>= 1) m = fmaxf(m, __shfl_xor(m, off));
        // correctly-rounded fp32 exp (center of all faithful-exp realizations)
        const float p = (float)exp((double)(v - m));
        // denominator: numpy pairwise_sum(64) = 8 strided accumulators + tree
        float racc[8];
        #pragma unroll
        for (int a = 0; a < 8; ++a) racc[a] = __shfl(p, a);
        #pragma unroll
        for (int t = 1; t < 8; ++t)
            #pragma unroll
            for (int a = 0; a < 8; ++a) racc[a] = racc[a] + __shfl(p, 8 * t + a);
        const float s = ((racc[0] + racc[1]) + (racc[2] + racc[3]))
                      + ((racc[4] + racc[5]) + (racc[6] + racc[7]));
        const float q = p / s;          // IEEE fp32 division, matches np
        ssum += q;

        // top-8 with TIE-TOLERANT ordering: np's dispatched SIMD exp collapses
        // ~1-ulp-apart inputs to equal fp32 scores, and its stable top-k then
        // orders such pairs BY INDEX.  Reproduce the tie set by quantizing the
        // sort key to 4-ulp bins (total order -> butterfly-safe); break bin
        // ties by lowest index.  Genuine rank gaps are ~4% relative, far
        // outside 4 ulp, so only degenerate pairs are affected.
        unsigned kk = __float_as_uint(q) & ~3u;   // q > 0 so uint order == float order
        float myw = 0.f; int myi = 0;
        #pragma unroll
        for (int k = 0; k < TOPK; ++k) {
            unsigned bvk = kk; int bi = lane;
            #pragma unroll
            for (int off = 32; off; off >>= 1) {
                unsigned ovk = __shfl_xor(bvk, off);
                int      oi  = __shfl_xor(bi, off);
                if (ovk > bvk || (ovk == bvk && oi < bi)) { bvk = ovk; bi = oi; }
            }
            const float swv = __shfl(q, bi);      // unquantized score of winner
            if (lane == k)  { myw = swv; myi = bi; }
            if (lane == bi) kk = 0u;
        }
        // weight-sum: numpy pairwise tree over the 8 selected (n=8 path)
        float g[8];
        #pragma unroll
        for (int a = 0; a < 8; ++a) g[a] = __shfl(myw, a);
        const float wsum = ((g[0] + g[1]) + (g[2] + g[3]))
                         + ((g[4] + g[5]) + (g[6] + g[7]));

        const long gt = t0 + tok;
        if (lane < TOPK) {
            out_idx[gt * TOPK + lane] = (float)myi;
            out_w [gt * TOPK + lane] = myw / (wsum + 1e-20f);
            atomicAdd(&ce_loc[myi], 1u);
        }
    }

    sred[wid][lane] = ssum;
    __syncthreads();
    if (tid < NE) {
        float t = sred[0][tid] + sred[1][tid] + sred[2][tid] + sred[3][tid];
        atomicAdd(&ws_ssum[b * NE + tid], t);
        atomicAdd(&ws_ce  [b * NE + tid], (float)ce_loc[tid]);
    }
}

__global__ void moe_gate_aux(const float* __restrict__ ws_ce,
                             const float* __restrict__ ws_ssum,
                             float* __restrict__ out_aux)
{
    const int lane = threadIdx.x;   // 64 threads
    float part = 0.f;
    #pragma unroll
    for (int b = 0; b < NB; ++b)
        part += ws_ce[b * NE + lane] * ws_ssum[b * NE + lane];
    #pragma unroll
    for (int off = 32; off; off >>= 1) part += __shfl_xor(part, off);
    if (lane == 0)
        // aux = 0.1 * mean_b( sum_e (ce/(SEQ*K/E)) * (ssum/SEQ) )
        out_aux[0] = part * (0.1f / (4.0f * 512.0f * 4096.0f));
}

extern "C" void kernel_launch(void* const* d_in, const int* in_sizes, int n_in,
                              void* d_out, int out_size, void* d_ws, size_t ws_size,
                              hipStream_t stream)
{
    const float* x = (const float*)d_in[0];
    const float* w = (const float*)d_in[1];
    float* out      = (float*)d_out;
    float* out_idx  = out;                          // 16384*8 = 131072
    float* out_w    = out + (long)N_TOK * TOPK;     // 131072
    float* out_aux  = out + 2L * N_TOK * TOPK;      // 1
    float* ws_ce    = (float*)d_ws;                 // [4][64]
    float* ws_ssum  = ws_ce + NB * NE;              // [4][64]

    hipMemsetAsync(d_ws, 0, 2 * NB * NE * sizeof(float), stream);
    moe_gate_main<<<N_TOK / TT, 256, 0, stream>>>(x, w, out_idx, out_w, ws_ce, ws_ssum);
    moe_gate_aux<<<1, 64, 0, stream>>>(ws_ce, ws_ssum, out_aux);
}

// Round 12
// 446.291 us; speedup vs baseline: 2.9225x; 2.9225x over previous
//
#include <hip/hip_runtime.h>
#include <math.h>

#define N_TOK 16384
#define HDIM 2048
#define NE 64
#define TOPK 8
#define NB 4
#define SEQ 4096
#define TT 64        // tokens per block
#define HC 64        // H-chunk staged per iteration
#define LSTR 68      // LDS staging row stride (floats): 68%32=4 -> 2-way alias (free)
#define SSTR 65      // score tile row stride

__global__ __launch_bounds__(256) void moe_gate_main(
    const float* __restrict__ x, const float* __restrict__ w,
    float* __restrict__ out_idx, float* __restrict__ out_w,
    float* __restrict__ ws_ce, float* __restrict__ ws_ssum)
{
    __shared__ float xs[TT][LSTR];
    __shared__ float wl[NE][LSTR];
    __shared__ float sc[TT][SSTR];
    __shared__ unsigned ce_loc[NE];
    __shared__ float sred[4][NE];

    const int tid = threadIdx.x;
    const int blk = blockIdx.x;
    const int t0  = blk * TT;
    const int tx  = tid & 15;   // expert group: experts {tx, tx+16, tx+32, tx+48}
    const int ty  = tid >> 4;   // token group:  tokens  {ty, ty+16, ty+32, ty+48}

    if (tid < NE) ce_loc[tid] = 0u;

    // np.einsum fp32 emulation: 4 lane-partials per (token,expert).
    // lane l accumulates products at h ≡ l (mod 4).
    float4 acc[4][4];
    #pragma unroll
    for (int i = 0; i < 4; ++i)
        #pragma unroll
        for (int j = 0; j < 4; ++j) acc[i][j] = make_float4(0.f, 0.f, 0.f, 0.f);

    // register prefetch buffers (double-buffer the global->LDS staging)
    float4 xr[4], wr[4];
    #pragma unroll
    for (int r = 0; r < 4; ++r) {
        int f = tid + r * 256;              // flat float4 index in [0,1024)
        int row = f >> 4, h4 = f & 15;      // 16 float4 per 64-float row
        xr[r] = *(const float4*)&x[(long)(t0 + row) * HDIM + (h4 << 2)];
        wr[r] = *(const float4*)&w[(long)row * HDIM + (h4 << 2)];
    }

    // numpy einsum x4-unroll chain adds sub-vectors in order 3,2,1,0 within
    // each 16-float block; blocks ascend.  h4 visit order per 64-float chunk:
    const int qord[16] = {3,2,1,0, 7,6,5,4, 11,10,9,8, 15,14,13,12};

    for (int hc = 0; hc < HDIM; hc += HC) {
        #pragma unroll
        for (int r = 0; r < 4; ++r) {
            int f = tid + r * 256;
            int row = f >> 4, h4 = f & 15;
            *(float4*)&xs[row][h4 << 2] = xr[r];
            *(float4*)&wl[row][h4 << 2] = wr[r];
        }
        __syncthreads();
        if (hc + HC < HDIM) {
            #pragma unroll
            for (int r = 0; r < 4; ++r) {
                int f = tid + r * 256;
                int row = f >> 4, h4 = f & 15;
                xr[r] = *(const float4*)&x[(long)(t0 + row) * HDIM + hc + HC + (h4 << 2)];
                wr[r] = *(const float4*)&w[(long)row * HDIM + hc + HC + (h4 << 2)];
            }
        }
        #pragma unroll
        for (int qi = 0; qi < 16; ++qi) {
            const int h4 = qord[qi];
            float4 xv[4], wv[4];
            #pragma unroll
            for (int i = 0; i < 4; ++i) xv[i] = *(const float4*)&xs[ty + 16 * i][h4 << 2];
            #pragma unroll
            for (int j = 0; j < 4; ++j) wv[j] = *(const float4*)&wl[tx + 16 * j][h4 << 2];
            {
                // numpy SSE3-baseline npyv_muladd = mul then add, SEPARATE
                // roundings.  contract(off) forbids FMA fusion in this scope
                // — bit-identical to the previous asm-barrier version, but
                // leaves the scheduler/register-allocator free (the asm
                // barriers caused 2.4 GB of scratch spill traffic, r6 PMC).
                #pragma clang fp contract(off)
                #pragma unroll
                for (int i = 0; i < 4; ++i)
                    #pragma unroll
                    for (int j = 0; j < 4; ++j) {
                        acc[i][j].x = acc[i][j].x + xv[i].x * wv[j].x;
                        acc[i][j].y = acc[i][j].y + xv[i].y * wv[j].y;
                        acc[i][j].z = acc[i][j].z + xv[i].z * wv[j].z;
                        acc[i][j].w = acc[i][j].w + xv[i].w * wv[j].w;
                    }
            }
        }
        __syncthreads();
    }

    // horizontal combine, numpy npyv_sum (SSE3 hadd): (s0+s1)+(s2+s3)
    #pragma unroll
    for (int i = 0; i < 4; ++i)
        #pragma unroll
        for (int j = 0; j < 4; ++j) {
            float4 a = acc[i][j];
            sc[ty + 16 * i][tx + 16 * j] = (a.x + a.y) + (a.z + a.w);
        }
    __syncthreads();

    // epilogue: per wave, lane = expert; 16 tokens per wave (numpy fp32 emulation)
    const int wid  = tid >> 6;
    const int lane = tid & 63;
    const int b    = blk >> 6;          // SEQ/TT = 64 blocks per batch
    float ssum = 0.f;

    for (int r = 0; r < 16; ++r) {
        const int tok = wid * 16 + r;
        const float v = sc[tok][lane];
        // max over 64 experts (exact, order-free)
        float m = v;
        #pragma unroll
        for (int off = 32; off; off >>= 1) m = fmaxf(m, __shfl_xor(m, off));
        // correctly-rounded fp32 exp (center of all faithful-exp realizations)
        const float p = (float)exp((double)(v - m));
        // denominator: numpy pairwise_sum(64) = 8 strided accumulators + tree
        float racc[8];
        #pragma unroll
        for (int a = 0; a < 8; ++a) racc[a] = __shfl(p, a);
        #pragma unroll
        for (int t = 1; t < 8; ++t)
            #pragma unroll
            for (int a = 0; a < 8; ++a) racc[a] = racc[a] + __shfl(p, 8 * t + a);
        const float s = ((racc[0] + racc[1]) + (racc[2] + racc[3]))
                      + ((racc[4] + racc[5]) + (racc[6] + racc[7]));
        const float q = p / s;          // IEEE fp32 division, matches np
        ssum += q;

        // top-8 with TIE-TOLERANT ordering: np's dispatched SIMD exp collapses
        // ~1-ulp-apart inputs to equal fp32 scores, and its stable top-k then
        // orders such pairs BY INDEX.  Reproduce the tie set by quantizing the
        // sort key to 4-ulp bins (total order -> butterfly-safe); break bin
        // ties by lowest index.  Genuine rank gaps are ~4% relative, far
        // outside 4 ulp, so only degenerate pairs are affected.
        unsigned kk = __float_as_uint(q) & ~3u;   // q > 0 so uint order == float order
        float myw = 0.f; int myi = 0;
        #pragma unroll
        for (int k = 0; k < TOPK; ++k) {
            unsigned bvk = kk; int bi = lane;
            #pragma unroll
            for (int off = 32; off; off >>= 1) {
                unsigned ovk = __shfl_xor(bvk, off);
                int      oi  = __shfl_xor(bi, off);
                if (ovk > bvk || (ovk == bvk && oi < bi)) { bvk = ovk; bi = oi; }
            }
            const float swv = __shfl(q, bi);      // unquantized score of winner
            if (lane == k)  { myw = swv; myi = bi; }
            if (lane == bi) kk = 0u;
        }
        // weight-sum: numpy pairwise tree over the 8 selected (n=8 path)
        float g[8];
        #pragma unroll
        for (int a = 0; a < 8; ++a) g[a] = __shfl(myw, a);
        const float wsum = ((g[0] + g[1]) + (g[2] + g[3]))
                         + ((g[4] + g[5]) + (g[6] + g[7]));

        const long gt = t0 + tok;
        if (lane < TOPK) {
            out_idx[gt * TOPK + lane] = (float)myi;
            out_w [gt * TOPK + lane] = myw / (wsum + 1e-20f);
            atomicAdd(&ce_loc[myi], 1u);
        }
    }

    sred[wid][lane] = ssum;
    __syncthreads();
    if (tid < NE) {
        float t = sred[0][tid] + sred[1][tid] + sred[2][tid] + sred[3][tid];
        atomicAdd(&ws_ssum[b * NE + tid], t);
        atomicAdd(&ws_ce  [b * NE + tid], (float)ce_loc[tid]);
    }
}

__global__ void moe_gate_aux(const float* __restrict__ ws_ce,
                             const float* __restrict__ ws_ssum,
                             float* __restrict__ out_aux)
{
    const int lane = threadIdx.x;   // 64 threads
    float part = 0.f;
    #pragma unroll
    for (int b = 0; b < NB; ++b)
        part += ws_ce[b * NE + lane] * ws_ssum[b * NE + lane];
    #pragma unroll
    for (int off = 32; off; off >>= 1) part += __shfl_xor(part, off);
    if (lane == 0)
        // aux = 0.1 * mean_b( sum_e (ce/(SEQ*K/E)) * (ssum/SEQ) )
        out_aux[0] = part * (0.1f / (4.0f * 512.0f * 4096.0f));
}

extern "C" void kernel_launch(void* const* d_in, const int* in_sizes, int n_in,
                              void* d_out, int out_size, void* d_ws, size_t ws_size,
                              hipStream_t stream)
{
    const float* x = (const float*)d_in[0];
    const float* w = (const float*)d_in[1];
    float* out      = (float*)d_out;
    float* out_idx  = out;                          // 16384*8 = 131072
    float* out_w    = out + (long)N_TOK * TOPK;     // 131072
    float* out_aux  = out + 2L * N_TOK * TOPK;      // 1
    float* ws_ce    = (float*)d_ws;                 // [4][64]
    float* ws_ssum  = ws_ce + NB * NE;              // [4][64]

    hipMemsetAsync(d_ws, 0, 2 * NB * NE * sizeof(float), stream);
    moe_gate_main<<<N_TOK / TT, 256, 0, stream>>>(x, w, out_idx, out_w, ws_ce, ws_ssum);
    moe_gate_aux<<<1, 64, 0, stream>>>(ws_ce, ws_ssum, out_aux);
}

// Round 14
// 439.308 us; speedup vs baseline: 2.9689x; 1.0159x over previous
//
#include <hip/hip_runtime.h>
#include <math.h>

#define N_TOK 16384
#define HDIM 2048
#define NE 64
#define TOPK 8
#define NB 4
#define SEQ 4096
#define TT 64        // tokens per block
#define HC 64        // H-chunk staged per iteration
#define LSTR 68      // LDS staging row stride (floats): 68%32=4 -> 2-way alias (free)
#define SSTR 65      // score tile row stride

// Load one qi-step's fragments (8 x ds_read_b128) into named register buffers.
#define LOADQ(XV, WV, H4C) do {                                                  \
    _Pragma("unroll")                                                            \
    for (int i = 0; i < 4; ++i) XV[i] = *(const float4*)&xs[ty + 16*i][(H4C) << 2]; \
    _Pragma("unroll")                                                            \
    for (int j = 0; j < 4; ++j) WV[j] = *(const float4*)&wl[tx + 16*j][(H4C) << 2]; \
} while (0)

// numpy SSE3-baseline npyv_muladd = mul then add, SEPARATE roundings.
// contract(off) forbids FMA fusion in this scope (bit-exact numpy emulation).
#define COMPQ(XV, WV) do {                                                       \
    _Pragma("clang fp contract(off)")                                            \
    _Pragma("unroll")                                                            \
    for (int i = 0; i < 4; ++i) {                                                \
        _Pragma("unroll")                                                        \
        for (int j = 0; j < 4; ++j) {                                            \
            acc[i][j].x = acc[i][j].x + XV[i].x * WV[j].x;                       \
            acc[i][j].y = acc[i][j].y + XV[i].y * WV[j].y;                       \
            acc[i][j].z = acc[i][j].z + XV[i].z * WV[j].z;                       \
            acc[i][j].w = acc[i][j].w + XV[i].w * WV[j].w;                       \
        }                                                                        \
    }                                                                            \
} while (0)

__global__ __launch_bounds__(256) void moe_gate_main(
    const float* __restrict__ x, const float* __restrict__ w,
    float* __restrict__ out_idx, float* __restrict__ out_w,
    float* __restrict__ ws_ce, float* __restrict__ ws_ssum)
{
    __shared__ float xs[TT][LSTR];
    __shared__ float wl[NE][LSTR];
    __shared__ float sc[TT][SSTR];
    __shared__ unsigned ce_loc[NE];
    __shared__ float sred[4][NE];

    const int tid = threadIdx.x;
    const int blk = blockIdx.x;
    const int t0  = blk * TT;
    const int tx  = tid & 15;   // expert group: experts {tx, tx+16, tx+32, tx+48}
    const int ty  = tid >> 4;   // token group:  tokens  {ty, ty+16, ty+32, ty+48}

    if (tid < NE) ce_loc[tid] = 0u;

    // np.einsum fp32 emulation: 4 lane-partials per (token,expert).
    float4 acc[4][4];
    #pragma unroll
    for (int i = 0; i < 4; ++i)
        #pragma unroll
        for (int j = 0; j < 4; ++j) acc[i][j] = make_float4(0.f, 0.f, 0.f, 0.f);

    // register prefetch buffers (double-buffer the global->LDS staging)
    float4 xr[4], wr[4];
    #pragma unroll
    for (int r = 0; r < 4; ++r) {
        int f = tid + r * 256;              // flat float4 index in [0,1024)
        int row = f >> 4, h4 = f & 15;      // 16 float4 per 64-float row
        xr[r] = *(const float4*)&x[(long)(t0 + row) * HDIM + (h4 << 2)];
        wr[r] = *(const float4*)&w[(long)row * HDIM + (h4 << 2)];
    }

    // numpy einsum x4-unroll chain adds sub-vectors in order 3,2,1,0 within
    // each 16-float block; blocks ascend.  h4 visit order per 64-float chunk:
    const int qord[16] = {3,2,1,0, 7,6,5,4, 11,10,9,8, 15,14,13,12};

    for (int hc = 0; hc < HDIM; hc += HC) {
        #pragma unroll
        for (int r = 0; r < 4; ++r) {
            int f = tid + r * 256;
            int row = f >> 4, h4 = f & 15;
            *(float4*)&xs[row][h4 << 2] = xr[r];
            *(float4*)&wl[row][h4 << 2] = wr[r];
        }
        __syncthreads();
        if (hc + HC < HDIM) {
            #pragma unroll
            for (int r = 0; r < 4; ++r) {
                int f = tid + r * 256;
                int row = f >> 4, h4 = f & 15;
                xr[r] = *(const float4*)&x[(long)(t0 + row) * HDIM + hc + HC + (h4 << 2)];
                wr[r] = *(const float4*)&w[(long)row * HDIM + hc + HC + (h4 << 2)];
            }
        }

        // 2-deep software-pipelined qi loop: issue ALL 8 LDS loads of step
        // qi+1 before computing step qi, so the ~120cy ds_read latency hides
        // under ~256cy of VALU.  (r12 PMC: 1 wave/SIMD -> just-in-time loads
        // exposed full latency per read; VALUBusy 31%.)  Arithmetic order is
        // IDENTICAL to the sequential qord walk.
        {
            float4 xva[4], wva[4], xvb[4], wvb[4];
            LOADQ(xva, wva, qord[0]);
            #pragma unroll
            for (int qp = 0; qp < 8; ++qp) {
                LOADQ(xvb, wvb, qord[2 * qp + 1]);
                COMPQ(xva, wva);
                if (qp < 7) LOADQ(xva, wva, qord[2 * qp + 2]);
                COMPQ(xvb, wvb);
            }
        }
        __syncthreads();
    }

    // horizontal combine, numpy npyv_sum (SSE3 hadd): (s0+s1)+(s2+s3)
    #pragma unroll
    for (int i = 0; i < 4; ++i)
        #pragma unroll
        for (int j = 0; j < 4; ++j) {
            float4 a = acc[i][j];
            sc[ty + 16 * i][tx + 16 * j] = (a.x + a.y) + (a.z + a.w);
        }
    __syncthreads();

    // epilogue: per wave, lane = expert; 16 tokens per wave (numpy fp32 emulation)
    const int wid  = tid >> 6;
    const int lane = tid & 63;
    const int b    = blk >> 6;          // SEQ/TT = 64 blocks per batch
    float ssum = 0.f;

    for (int r = 0; r < 16; ++r) {
        const int tok = wid * 16 + r;
        const float v = sc[tok][lane];
        // max over 64 experts (exact, order-free)
        float m = v;
        #pragma unroll
        for (int off = 32; off; off >>= 1) m = fmaxf(m, __shfl_xor(m, off));
        // correctly-rounded fp32 exp (center of all faithful-exp realizations)
        const float p = (float)exp((double)(v - m));
        // denominator: numpy pairwise_sum(64) = 8 strided accumulators + tree
        float racc[8];
        #pragma unroll
        for (int a = 0; a < 8; ++a) racc[a] = __shfl(p, a);
        #pragma unroll
        for (int t = 1; t < 8; ++t)
            #pragma unroll
            for (int a = 0; a < 8; ++a) racc[a] = racc[a] + __shfl(p, 8 * t + a);
        const float s = ((racc[0] + racc[1]) + (racc[2] + racc[3]))
                      + ((racc[4] + racc[5]) + (racc[6] + racc[7]));
        const float q = p / s;          // IEEE fp32 division, matches np
        ssum += q;

        // top-8 with TIE-TOLERANT ordering (see r6 notes): quantize sort key
        // to 4-ulp bins, break bin ties by lowest index (np stable top-k).
        unsigned kk = __float_as_uint(q) & ~3u;   // q > 0: uint order == float order
        float myw = 0.f; int myi = 0;
        #pragma unroll
        for (int k = 0; k < TOPK; ++k) {
            unsigned bvk = kk; int bi = lane;
            #pragma unroll
            for (int off = 32; off; off >>= 1) {
                unsigned ovk = __shfl_xor(bvk, off);
                int      oi  = __shfl_xor(bi, off);
                if (ovk > bvk || (ovk == bvk && oi < bi)) { bvk = ovk; bi = oi; }
            }
            const float swv = __shfl(q, bi);      // unquantized score of winner
            if (lane == k)  { myw = swv; myi = bi; }
            if (lane == bi) kk = 0u;
        }
        // weight-sum: numpy pairwise tree over the 8 selected (n=8 path)
        float g[8];
        #pragma unroll
        for (int a = 0; a < 8; ++a) g[a] = __shfl(myw, a);
        const float wsum = ((g[0] + g[1]) + (g[2] + g[3]))
                         + ((g[4] + g[5]) + (g[6] + g[7]));

        const long gt = t0 + tok;
        if (lane < TOPK) {
            out_idx[gt * TOPK + lane] = (float)myi;
            out_w [gt * TOPK + lane] = myw / (wsum + 1e-20f);
            atomicAdd(&ce_loc[myi], 1u);
        }
    }

    sred[wid][lane] = ssum;
    __syncthreads();
    if (tid < NE) {
        float t = sred[0][tid] + sred[1][tid] + sred[2][tid] + sred[3][tid];
        atomicAdd(&ws_ssum[b * NE + tid], t);
        atomicAdd(&ws_ce  [b * NE + tid], (float)ce_loc[tid]);
    }
}

__global__ void moe_gate_aux(const float* __restrict__ ws_ce,
                             const float* __restrict__ ws_ssum,
                             float* __restrict__ out_aux)
{
    const int lane = threadIdx.x;   // 64 threads
    float part = 0.f;
    #pragma unroll
    for (int b = 0; b < NB; ++b)
        part += ws_ce[b * NE + lane] * ws_ssum[b * NE + lane];
    #pragma unroll
    for (int off = 32; off; off >>= 1) part += __shfl_xor(part, off);
    if (lane == 0)
        // aux = 0.1 * mean_b( sum_e (ce/(SEQ*K/E)) * (ssum/SEQ) )
        out_aux[0] = part * (0.1f / (4.0f * 512.0f * 4096.0f));
}

extern "C" void kernel_launch(void* const* d_in, const int* in_sizes, int n_in,
                              void* d_out, int out_size, void* d_ws, size_t ws_size,
                              hipStream_t stream)
{
    const float* x = (const float*)d_in[0];
    const float* w = (const float*)d_in[1];
    float* out      = (float*)d_out;
    float* out_idx  = out;                          // 16384*8 = 131072
    float* out_w    = out + (long)N_TOK * TOPK;     // 131072
    float* out_aux  = out + 2L * N_TOK * TOPK;      // 1
    float* ws_ce    = (float*)d_ws;                 // [4][64]
    float* ws_ssum  = ws_ce + NB * NE;              // [4][64]

    hipMemsetAsync(d_ws, 0, 2 * NB * NE * sizeof(float), stream);
    moe_gate_main<<<N_TOK / TT, 256, 0, stream>>>(x, w, out_idx, out_w, ws_ce, ws_ssum);
    moe_gate_aux<<<1, 64, 0, stream>>>(ws_ce, ws_ssum, out_aux);
}